// Round 6
// baseline (345.640 us; speedup 1.0000x reference)
//
#include <hip/hip_runtime.h>
#include <hip/hip_cooperative_groups.h>

namespace cg = cooperative_groups;

// SelfAttention2D: B=4, N=4096, C=256, R=32, fp32 in/out.
// out = gamma * ((softmax_axis1(f g^T) h) w_v) + x.
// Single cooperative kernel, 5 phases separated by grid.sync():
//   P0 weight->B-frag prep | P1 f,g,h projections | P2 column sums (axis=1
//   softmax denominator; |s|*log2e < 64 << 128 so no max pass) | P3 PV with
//   LDS D->A layout transform | P4 y@w_v + gamma*() + x residual.
// All four matmuls on bf16 MFMA 16x16x32. f pre-scaled by log2(e) -> raw v_exp.

#define BB 4
#define NN 4096
#define CC 256
#define RR 32
#define CSEG 4   // n-split for colsum
#define PSEG 4   // m-split for pv
#define MP 40    // P-tile row stride (ushorts)
#define LOG2E 1.44269504088896340736f

typedef short short8 __attribute__((ext_vector_type(8)));   // 8 bf16
typedef float floatx4 __attribute__((ext_vector_type(4)));  // MFMA C/D

#define MFMA16 __builtin_amdgcn_mfma_f32_16x16x32_bf16

static __device__ __forceinline__ unsigned short f2bf(float f) {
  union { float f; unsigned u; } v; v.f = f;
  const unsigned r = v.u + 0x7fffu + ((v.u >> 16) & 1u);  // RNE
  return (unsigned short)(r >> 16);
}
// pack trunc-bf16(lo), trunc-bf16(hi) into one uint via v_perm_b32
static __device__ __forceinline__ unsigned bfpack(float lo, float hi) {
  return __builtin_amdgcn_perm(__float_as_uint(hi), __float_as_uint(lo), 0x07060302u);
}

#define C_ADDR(TN, TM) (((TN) + col) * MP + (TM) + q * 4)

__global__ __launch_bounds__(256, 2) void k_all(
    const float* __restrict__ x, const float* __restrict__ wf,
    const float* __restrict__ wg, const float* __restrict__ wh,
    const float* __restrict__ wv, const float* __restrict__ gamma,
    float* __restrict__ out,
    unsigned short* __restrict__ wfrag, unsigned short* __restrict__ wvfrag,
    unsigned short* __restrict__ f16, unsigned short* __restrict__ g16,
    unsigned short* __restrict__ hT16, float* __restrict__ psum,
    float* __restrict__ py) {
  cg::grid_group gg = cg::this_grid();
  __shared__ __align__(16) unsigned char smem[16896];
  const int tid = threadIdx.x, lane = tid & 63, wave = tid >> 6;
  const int col = lane & 15, q = lane >> 4;
  const int blk = blockIdx.x;
  const floatx4 zero = {0.f, 0.f, 0.f, 0.f};

  // ---------------- P0: pack weights into B-frag bf16 layout ----------------
  {
    const int idx = blk * 256 + tid;  // grid covers 131072 >= 32768
    if (idx < 24576) {
      const int mat = idx >> 13;
      const int fid = (idx >> 9) & 15;
      const int kc = fid >> 1, nt = fid & 1;
      const int l2 = (idx >> 3) & 63, j = idx & 7;
      const int c2 = l2 & 15, q2 = l2 >> 4;
      const float* w = (mat == 0) ? wf : ((mat == 1) ? wg : wh);
      wfrag[idx] = f2bf(w[(kc * 32 + q2 * 8 + j) * RR + nt * 16 + c2]);
    } else if (idx < 32768) {
      const int r = idx - 24576;
      const int t = (r >> 9) & 15;
      const int l2 = (r >> 3) & 63, j = r & 7;
      const int c2 = l2 & 15, q2 = l2 >> 4;
      wvfrag[r] = f2bf(wv[(q2 * 8 + j) * CC + t * 16 + c2]);
    }
  }
  gg.sync();

  // ---------------- P1: f,g,h = x @ {wf,wg,wh}  (waves 0,1: 16 tokens each)
  if (wave < 2) {
    const int t0 = blk * 32 + wave * 16;
    short8 af[8];
    const float* xr = x + (long)(t0 + col) * CC + q * 8;
#pragma unroll
    for (int kc = 0; kc < 8; ++kc) {
      float tmp[8];
      *(float4*)(tmp) = *(const float4*)(xr + kc * 32);
      *(float4*)(tmp + 4) = *(const float4*)(xr + kc * 32 + 4);
      short8 o;
#pragma unroll
      for (int j = 0; j < 8; ++j) o[j] = (short)f2bf(tmp[j]);
      af[kc] = o;
    }
    floatx4 acc[3][2];
#pragma unroll
    for (int m = 0; m < 3; ++m) { acc[m][0] = zero; acc[m][1] = zero; }
    const short8* wfr = (const short8*)wfrag;
#pragma unroll
    for (int kc = 0; kc < 8; ++kc) {
#pragma unroll
      for (int mat = 0; mat < 3; ++mat) {
#pragma unroll
        for (int nt = 0; nt < 2; ++nt) {
          const short8 bf = wfr[(mat * 16 + kc * 2 + nt) * 64 + lane];
          acc[mat][nt] = MFMA16(af[kc], bf, acc[mat][nt], 0, 0, 0);
        }
      }
    }
    const int b = t0 >> 12;
#pragma unroll
    for (int nt = 0; nt < 2; ++nt) {
#pragma unroll
      for (int r = 0; r < 4; ++r) {
        const int tok = t0 + q * 4 + r;
        const int n = nt * 16 + col;
        f16[(long)tok * RR + n] = f2bf(acc[0][nt][r] * LOG2E);
        g16[(long)tok * RR + n] = f2bf(acc[1][nt][r]);
        hT16[((long)b * RR + n) * NN + (tok & (NN - 1))] = f2bf(acc[2][nt][r]);
      }
    }
  }
  gg.sync();

  // ---------------- P2: partial colsum[m] = sum_n exp2(s'[n,m]) ----------------
  {
    const int mblk = blk & 31, b = (blk >> 5) & 3, seg = blk >> 7;
    const int m0 = mblk * 128 + wave * 32;
    const short8 bg1 = *(const short8*)(g16 + ((long)(b * NN + m0 + col)) * RR + q * 8);
    const short8 bg2 = *(const short8*)(g16 + ((long)(b * NN + m0 + 16 + col)) * RR + q * 8);
    float s1 = 0.f, s2 = 0.f;
    const unsigned short* fb = f16 + ((long)b * NN + seg * (NN / CSEG)) * RR;
#pragma unroll 4
    for (int n = 0; n < NN / CSEG; n += 16) {
      const short8 af = *(const short8*)(fb + (long)(n + col) * RR + q * 8);
      const floatx4 d1 = MFMA16(af, bg1, zero, 0, 0, 0);
      const floatx4 d2 = MFMA16(af, bg2, zero, 0, 0, 0);
      s1 += __builtin_amdgcn_exp2f(d1[0]) + __builtin_amdgcn_exp2f(d1[1]) +
            __builtin_amdgcn_exp2f(d1[2]) + __builtin_amdgcn_exp2f(d1[3]);
      s2 += __builtin_amdgcn_exp2f(d2[0]) + __builtin_amdgcn_exp2f(d2[1]) +
            __builtin_amdgcn_exp2f(d2[2]) + __builtin_amdgcn_exp2f(d2[3]);
    }
    s1 += __shfl_xor(s1, 16); s1 += __shfl_xor(s1, 32);
    s2 += __shfl_xor(s2, 16); s2 += __shfl_xor(s2, 32);
    if (lane < 16) {
      psum[(long)seg * (BB * NN) + b * NN + m0 + lane] = s1;
      psum[(long)seg * (BB * NN) + b * NN + m0 + 16 + lane] = s2;
    }
  }
  gg.sync();

  // ---------------- P3: PV (S^T via swapped operands, LDS D->A transform)
  {
    unsigned short* pt = (unsigned short*)smem + wave * (32 * MP);  // 2560 B/wave
    float* cis = (float*)(smem + 4 * 32 * MP * 2);                  // offset 10240
    const int nblk = blk & 31, b = (blk >> 5) & 3, mseg = blk >> 7;
    const int n0 = nblk * 128 + wave * 32;
    const int mbase = mseg * (NN / PSEG);
    for (int i = tid; i < NN / PSEG; i += 256) {  // fused 1/colsum
      float s = 0.f;
#pragma unroll
      for (int sg = 0; sg < CSEG; ++sg)
        s += psum[(long)sg * (BB * NN) + b * NN + mbase + i];
      cis[i] = 1.0f / s;
    }
    __syncthreads();
    const short8 af1 = *(const short8*)(f16 + ((long)(b * NN + n0 + col)) * RR + q * 8);
    const short8 af2 = *(const short8*)(f16 + ((long)(b * NN + n0 + 16 + col)) * RR + q * 8);
    floatx4 a11 = zero, a12 = zero, a21 = zero, a22 = zero;
    const unsigned short* gb = g16 + (long)b * NN * RR;
    const unsigned short* hb = hT16 + (long)b * RR * NN;
    for (int mi = 0; mi < NN / PSEG; mi += 32) {
      const int m0 = mbase + mi;
      const short8 bg1 = *(const short8*)(gb + (long)(m0 + col) * RR + q * 8);
      const short8 bg2 = *(const short8*)(gb + (long)(m0 + 16 + col) * RR + q * 8);
      // S^T: A=g(m rows), B=f(n cols) -> lane(q,col): s'[n=col][m=q*4+r]
      const floatx4 d00 = MFMA16(bg1, af1, zero, 0, 0, 0);
      const floatx4 d01 = MFMA16(bg2, af1, zero, 0, 0, 0);
      const floatx4 d10 = MFMA16(bg1, af2, zero, 0, 0, 0);
      const floatx4 d11 = MFMA16(bg2, af2, zero, 0, 0, 0);
      const float4 cia = *(const float4*)(cis + mi + q * 4);
      const float4 cib = *(const float4*)(cis + mi + 16 + q * 4);
      float w0, w1, w2, w3;
      w0 = __builtin_amdgcn_exp2f(d00[0]) * cia.x; w1 = __builtin_amdgcn_exp2f(d00[1]) * cia.y;
      w2 = __builtin_amdgcn_exp2f(d00[2]) * cia.z; w3 = __builtin_amdgcn_exp2f(d00[3]) * cia.w;
      *(uint2*)(pt + C_ADDR(0, 0)) = make_uint2(bfpack(w0, w1), bfpack(w2, w3));
      w0 = __builtin_amdgcn_exp2f(d01[0]) * cib.x; w1 = __builtin_amdgcn_exp2f(d01[1]) * cib.y;
      w2 = __builtin_amdgcn_exp2f(d01[2]) * cib.z; w3 = __builtin_amdgcn_exp2f(d01[3]) * cib.w;
      *(uint2*)(pt + C_ADDR(0, 16)) = make_uint2(bfpack(w0, w1), bfpack(w2, w3));
      w0 = __builtin_amdgcn_exp2f(d10[0]) * cia.x; w1 = __builtin_amdgcn_exp2f(d10[1]) * cia.y;
      w2 = __builtin_amdgcn_exp2f(d10[2]) * cia.z; w3 = __builtin_amdgcn_exp2f(d10[3]) * cia.w;
      *(uint2*)(pt + C_ADDR(16, 0)) = make_uint2(bfpack(w0, w1), bfpack(w2, w3));
      w0 = __builtin_amdgcn_exp2f(d11[0]) * cib.x; w1 = __builtin_amdgcn_exp2f(d11[1]) * cib.y;
      w2 = __builtin_amdgcn_exp2f(d11[2]) * cib.z; w3 = __builtin_amdgcn_exp2f(d11[3]) * cib.w;
      *(uint2*)(pt + C_ADDR(16, 16)) = make_uint2(bfpack(w0, w1), bfpack(w2, w3));
      // read back as PV A-frags (same wave, lgkmcnt-ordered)
      const short8 ap1 = *(const short8*)(pt + col * MP + q * 8);
      const short8 ap2 = *(const short8*)(pt + (col + 16) * MP + q * 8);
      const short8 bh1 = *(const short8*)(hb + (long)col * NN + m0 + q * 8);
      const short8 bh2 = *(const short8*)(hb + (long)(col + 16) * NN + m0 + q * 8);
      a11 = MFMA16(ap1, bh1, a11, 0, 0, 0);
      a12 = MFMA16(ap1, bh2, a12, 0, 0, 0);
      a21 = MFMA16(ap2, bh1, a21, 0, 0, 0);
      a22 = MFMA16(ap2, bh2, a22, 0, 0, 0);
    }
    float* yp = py + (long)(mseg * BB + b) * NN * RR;
#pragma unroll
    for (int r = 0; r < 4; ++r) {
      yp[(long)(n0 + q * 4 + r) * RR + col]           = a11[r];
      yp[(long)(n0 + q * 4 + r) * RR + col + 16]      = a12[r];
      yp[(long)(n0 + 16 + q * 4 + r) * RR + col]      = a21[r];
      yp[(long)(n0 + 16 + q * 4 + r) * RR + col + 16] = a22[r];
    }
  }
  gg.sync();

  // ---------------- P4: out = gamma*(y @ w_v) + x  (waves 0,1) ----------------
  if (wave < 2) {
    float* pw = (float*)smem + wave * (16 * 132);  // 8448 B/wave
    const int t0 = blk * 32 + wave * 16;
    const int b = t0 >> 12;
    const int tloc = t0 & (NN - 1);
    float s[8] = {0.f, 0.f, 0.f, 0.f, 0.f, 0.f, 0.f, 0.f};
#pragma unroll
    for (int sg = 0; sg < PSEG; ++sg) {
      const float* p = py + ((long)(sg * BB + b) * NN + tloc + col) * RR + q * 8;
      const float4 u0 = *(const float4*)p;
      const float4 u1 = *(const float4*)(p + 4);
      s[0] += u0.x; s[1] += u0.y; s[2] += u0.z; s[3] += u0.w;
      s[4] += u1.x; s[5] += u1.y; s[6] += u1.z; s[7] += u1.w;
    }
    short8 ay;
#pragma unroll
    for (int j = 0; j < 8; ++j) ay[j] = (short)f2bf(s[j]);
    const float gm = gamma[0];
    const short8* wvf = (const short8*)wvfrag;
    const int tok = lane >> 2, cg2 = (lane & 3) * 4;
#pragma unroll
    for (int h = 0; h < 2; ++h) {
#pragma unroll
      for (int t = 0; t < 8; ++t) {
        const short8 bw = wvf[(h * 8 + t) * 64 + lane];
        const floatx4 d = MFMA16(ay, bw, zero, 0, 0, 0);
#pragma unroll
        for (int r = 0; r < 4; ++r) pw[(q * 4 + r) * 132 + t * 16 + col] = d[r];
      }
#pragma unroll
      for (int j = 0; j < 8; ++j) {
        const float4 v = *(const float4*)(pw + tok * 132 + cg2 + j * 16);
        const long gidx = (long)(t0 + tok) * CC + h * 128 + cg2 + j * 16;
        const float4 xv = *(const float4*)(x + gidx);
        float4 o;
        o.x = gm * v.x + xv.x; o.y = gm * v.y + xv.y;
        o.z = gm * v.z + xv.z; o.w = gm * v.w + xv.w;
        *(float4*)(out + gidx) = o;
      }
    }
  }
}

extern "C" void kernel_launch(void* const* d_in, const int* in_sizes, int n_in,
                              void* d_out, int out_size, void* d_ws, size_t ws_size,
                              hipStream_t stream) {
  const float* x = (const float*)d_in[0];
  const float* wf = (const float*)d_in[1];
  const float* wg = (const float*)d_in[2];
  const float* wh = (const float*)d_in[3];
  const float* wv = (const float*)d_in[4];
  const float* gamma = (const float*)d_in[5];
  float* out = (float*)d_out;

  unsigned short* wfrag = (unsigned short*)d_ws;         // 24576 bf16
  unsigned short* wvfrag = wfrag + 24576;                // 8192 bf16
  unsigned short* f16 = wvfrag + 8192;                   // B*N*R (x LOG2E)
  unsigned short* g16 = f16 + (long)BB * NN * RR;        // B*N*R
  unsigned short* hT16 = g16 + (long)BB * NN * RR;       // B*R*N
  float* psum = (float*)(hT16 + (long)BB * NN * RR);     // CSEG*B*N
  float* py = psum + (long)CSEG * BB * NN;               // PSEG*B*N*R

  void* args[] = {&x, &wf, &wg, &wh, &wv, &gamma, &out,
                  &wfrag, &wvfrag, &f16, &g16, &hT16, &psum, &py};
  hipLaunchCooperativeKernel((void*)k_all, dim3(512), dim3(256), args, 0, stream);
}

// Round 7
// 152.982 us; speedup vs baseline: 2.2594x; 2.2594x over previous
//
#include <hip/hip_runtime.h>

// SelfAttention2D: B=4, N=4096, C=256, R=32, fp32 in/out.
// out = gamma * ((softmax_axis1(f g^T) h) w_v) + x.
// 3 kernels: k_fgh (projections, weights packed in-block), k_colsum
// (softmax-axis=1 denominators), k_pvout (PV + w_v projection + residual,
// m-split kept inside the block so partials live in LDS, not global).
// All matmuls on bf16 MFMA 16x16x32. f pre-scaled by log2(e) -> raw v_exp.
// |s|*log2e < 64 << 128 so exp2 needs no max-subtraction pass.
// NOTE (R6 lesson): grid.sync() costs ~50us at 512 blocks on MI355X — never
// fuse phases through it; block-local fusion only.

#define BB 4
#define NN 4096
#define CC 256
#define RR 32
#define CSEG 4   // n-split for colsum
#define MP 40    // P-tile row stride (ushorts)
#define LOG2E 1.44269504088896340736f

typedef short short8 __attribute__((ext_vector_type(8)));   // 8 bf16
typedef float floatx4 __attribute__((ext_vector_type(4)));  // MFMA C/D

#define MFMA16 __builtin_amdgcn_mfma_f32_16x16x32_bf16

static __device__ __forceinline__ unsigned short f2bf(float f) {
  union { float f; unsigned u; } v; v.f = f;
  const unsigned r = v.u + 0x7fffu + ((v.u >> 16) & 1u);  // RNE
  return (unsigned short)(r >> 16);
}
// pack trunc-bf16(lo), trunc-bf16(hi) into one uint via v_perm_b32
static __device__ __forceinline__ unsigned bfpack(float lo, float hi) {
  return __builtin_amdgcn_perm(__float_as_uint(hi), __float_as_uint(lo), 0x07060302u);
}

// --------------- k_fgh: f,g,h = x @ {wf,wg,wh}; weights packed into LDS
__global__ __launch_bounds__(256) void k_fgh(
    const float* __restrict__ x, const float* __restrict__ wf,
    const float* __restrict__ wg, const float* __restrict__ wh,
    unsigned short* __restrict__ f16, unsigned short* __restrict__ g16,
    unsigned short* __restrict__ hT16) {
  __shared__ unsigned short wflds[24576];  // 48 KB: 3 mats x 16 frags x 64 lanes x 8
  const int tid = threadIdx.x, lane = tid & 63, wave = tid >> 6;
  const int col = lane & 15, q = lane >> 4;
  // pack: coalesced float4 reads, scattered ds_write_b16
  for (int s4 = tid; s4 < 6144; s4 += 256) {
    const int mat = s4 >> 11;
    const int s = (s4 & 2047) << 2;          // element index within w (8192)
    const int rr = s >> 5, c = s & 31;       // w[rr][c], c % 4 == 0
    const float* w = (mat == 0) ? wf : ((mat == 1) ? wg : wh);
    const float4 v = *(const float4*)(w + s);
    const int kc = rr >> 5, q2 = (rr >> 3) & 3, j = rr & 7;
    const int base = (mat * 16 + kc * 2) * 512 + q2 * 128 + j;
    const float vv[4] = {v.x, v.y, v.z, v.w};
#pragma unroll
    for (int e = 0; e < 4; ++e) {
      const int ce = c + e;
      wflds[base + (ce >> 4) * 512 + (ce & 15) * 8] = f2bf(vv[e]);
    }
  }
  __syncthreads();
  const int t0 = blockIdx.x * 64 + wave * 16;
  short8 af[8];
  const float* xr = x + (long)(t0 + col) * CC + q * 8;
#pragma unroll
  for (int kc = 0; kc < 8; ++kc) {
    float tmp[8];
    *(float4*)(tmp) = *(const float4*)(xr + kc * 32);
    *(float4*)(tmp + 4) = *(const float4*)(xr + kc * 32 + 4);
    short8 o;
#pragma unroll
    for (int j = 0; j < 8; ++j) o[j] = (short)f2bf(tmp[j]);
    af[kc] = o;
  }
  const floatx4 zero = {0.f, 0.f, 0.f, 0.f};
  floatx4 acc[3][2];
#pragma unroll
  for (int m = 0; m < 3; ++m) { acc[m][0] = zero; acc[m][1] = zero; }
#pragma unroll
  for (int kc = 0; kc < 8; ++kc) {
#pragma unroll
    for (int mat = 0; mat < 3; ++mat) {
#pragma unroll
      for (int nt = 0; nt < 2; ++nt) {
        const short8 bf = *(const short8*)(wflds + (mat * 16 + kc * 2 + nt) * 512 + lane * 8);
        acc[mat][nt] = MFMA16(af[kc], bf, acc[mat][nt], 0, 0, 0);
      }
    }
  }
  const int b = t0 >> 12;
#pragma unroll
  for (int nt = 0; nt < 2; ++nt) {
#pragma unroll
    for (int r = 0; r < 4; ++r) {
      const int tok = t0 + q * 4 + r;
      const int n = nt * 16 + col;
      f16[(long)tok * RR + n] = f2bf(acc[0][nt][r] * LOG2E);
      g16[(long)tok * RR + n] = f2bf(acc[1][nt][r]);
      hT16[((long)b * RR + n) * NN + (tok & (NN - 1))] = f2bf(acc[2][nt][r]);
    }
  }
}

// --------------------- k_colsum: partial colsum[m] = sum_n exp2(s'[n,m])
__global__ __launch_bounds__(256) void k_colsum(
    const unsigned short* __restrict__ f16, const unsigned short* __restrict__ g16,
    float* __restrict__ psum) {
  const int tid = threadIdx.x, lane = tid & 63, wave = tid >> 6;
  const int col = lane & 15, q = lane >> 4;
  const int mblk = blockIdx.x & 31;
  const int b = (blockIdx.x >> 5) & 3;
  const int seg = blockIdx.x >> 7;
  const int m0 = mblk * 128 + wave * 32;
  const short8 bg1 = *(const short8*)(g16 + ((long)(b * NN + m0 + col)) * RR + q * 8);
  const short8 bg2 = *(const short8*)(g16 + ((long)(b * NN + m0 + 16 + col)) * RR + q * 8);
  const floatx4 zero = {0.f, 0.f, 0.f, 0.f};
  float s1 = 0.f, s2 = 0.f;
  const unsigned short* fb = f16 + ((long)b * NN + seg * (NN / CSEG)) * RR;
#pragma unroll 4
  for (int n = 0; n < NN / CSEG; n += 16) {
    const short8 af = *(const short8*)(fb + (long)(n + col) * RR + q * 8);
    const floatx4 d1 = MFMA16(af, bg1, zero, 0, 0, 0);
    const floatx4 d2 = MFMA16(af, bg2, zero, 0, 0, 0);
    s1 += __builtin_amdgcn_exp2f(d1[0]) + __builtin_amdgcn_exp2f(d1[1]) +
          __builtin_amdgcn_exp2f(d1[2]) + __builtin_amdgcn_exp2f(d1[3]);
    s2 += __builtin_amdgcn_exp2f(d2[0]) + __builtin_amdgcn_exp2f(d2[1]) +
          __builtin_amdgcn_exp2f(d2[2]) + __builtin_amdgcn_exp2f(d2[3]);
  }
  s1 += __shfl_xor(s1, 16); s1 += __shfl_xor(s1, 32);
  s2 += __shfl_xor(s2, 16); s2 += __shfl_xor(s2, 32);
  if (lane < 16) {
    psum[(long)seg * (BB * NN) + b * NN + m0 + lane] = s1;
    psum[(long)seg * (BB * NN) + b * NN + m0 + 16 + lane] = s2;
  }
}

// --------- k_pvout: PV with in-block m-halves + y@w_v + gamma*() + x residual
// Block = 32 tokens; wave w: tile = w&1 (16 tokens), half = w>>1 (2048 m).
// Partial y lives in LDS; epilogue fused. No grid-level dependency.
__global__ __launch_bounds__(256, 2) void k_pvout(
    const unsigned short* __restrict__ f16, const unsigned short* __restrict__ g16,
    const unsigned short* __restrict__ hT16, const float* __restrict__ psum,
    const float* __restrict__ wv, const float* __restrict__ x,
    const float* __restrict__ gamma, float* __restrict__ out) {
  __shared__ unsigned short wvlds[8192];     // 16 KB: w_v B-frags
  __shared__ float cis[NN];                  // 16 KB: 1/colsum, full m-range
  __shared__ unsigned short pt_all[4][16 * MP];  // 5 KB: P^T tiles
  __shared__ float ylds[4][16 * 36];         // 9 KB: y partials [tile*2+half]
  __shared__ float ot[2][16 * 132];          // 16.5 KB: out transpose
  const int tid = threadIdx.x, lane = tid & 63, wave = tid >> 6;
  const int col = lane & 15, q = lane >> 4;
  const int b = blockIdx.x >> 7;
  const int t0 = (blockIdx.x & 127) * 32 + (wave & 1) * 16;  // token base (in-batch)
  const int half = wave >> 1;
  // pack w_v B-frags (coalesced float4 reads)
  for (int s4 = tid; s4 < 2048; s4 += 256) {
    const int s = s4 << 2;
    const int rr = s >> 8, c = s & 255;
    const float4 v = *(const float4*)(wv + s);
    const int base = (rr >> 3) * 128 + (rr & 7);
    const float vv[4] = {v.x, v.y, v.z, v.w};
#pragma unroll
    for (int e = 0; e < 4; ++e) {
      const int ce = c + e;
      wvlds[(ce >> 4) * 512 + base + (ce & 15) * 8] = f2bf(vv[e]);
    }
  }
  // cis = 1 / colsum (merge CSEG partials)
  for (int i = tid; i < NN; i += 256) {
    float s = 0.f;
#pragma unroll
    for (int sg = 0; sg < CSEG; ++sg) s += psum[(long)sg * (BB * NN) + b * NN + i];
    cis[i] = 1.0f / s;
  }
  __syncthreads();
  const floatx4 zero = {0.f, 0.f, 0.f, 0.f};
  // B-frag of S^T for this wave's 16 tokens (loop-invariant)
  const short8 bf = *(const short8*)(f16 + ((long)(b * NN + t0 + col)) * RR + q * 8);
  floatx4 acc1 = zero, acc2 = zero;
  unsigned short* pt = &pt_all[wave][0];
  const unsigned short* gb = g16 + (long)b * NN * RR;
  const unsigned short* hb = hT16 + (long)b * RR * NN;
  const int m_end = half * 2048 + 2048;
#pragma unroll 2
  for (int mi = half * 2048; mi < m_end; mi += 32) {
    const short8 bg1 = *(const short8*)(gb + (long)(mi + col) * RR + q * 8);
    const short8 bg2 = *(const short8*)(gb + (long)(mi + 16 + col) * RR + q * 8);
    // S^T: A=g(m rows), B=f(n cols) -> lane(q,col): s'[n=col][m=mi+q*4+r]
    const floatx4 d0 = MFMA16(bg1, bf, zero, 0, 0, 0);
    const floatx4 d1 = MFMA16(bg2, bf, zero, 0, 0, 0);
    const float4 cia = *(const float4*)(cis + mi + q * 4);
    const float4 cib = *(const float4*)(cis + mi + 16 + q * 4);
    float w0, w1, w2, w3;
    w0 = __builtin_amdgcn_exp2f(d0[0]) * cia.x; w1 = __builtin_amdgcn_exp2f(d0[1]) * cia.y;
    w2 = __builtin_amdgcn_exp2f(d0[2]) * cia.z; w3 = __builtin_amdgcn_exp2f(d0[3]) * cia.w;
    *(uint2*)(pt + col * MP + q * 4) = make_uint2(bfpack(w0, w1), bfpack(w2, w3));
    w0 = __builtin_amdgcn_exp2f(d1[0]) * cib.x; w1 = __builtin_amdgcn_exp2f(d1[1]) * cib.y;
    w2 = __builtin_amdgcn_exp2f(d1[2]) * cib.z; w3 = __builtin_amdgcn_exp2f(d1[3]) * cib.w;
    *(uint2*)(pt + col * MP + 16 + q * 4) = make_uint2(bfpack(w0, w1), bfpack(w2, w3));
    // read back as PV A-frag (same wave, lgkmcnt-ordered): A[n=col][k=0..31]
    const short8 ap = *(const short8*)(pt + col * MP + q * 8);
    const short8 bh1 = *(const short8*)(hb + (long)col * NN + mi + q * 8);
    const short8 bh2 = *(const short8*)(hb + (long)(col + 16) * NN + mi + q * 8);
    acc1 = MFMA16(ap, bh1, acc1, 0, 0, 0);
    acc2 = MFMA16(ap, bh2, acc2, 0, 0, 0);
  }
  // stash y partial: [tile*2+half][token 0..15][r 0..31], row stride 36
  {
    float* yp = &ylds[(wave & 1) * 2 + half][0];
#pragma unroll
    for (int r = 0; r < 4; ++r) {
      yp[(q * 4 + r) * 36 + col] = acc1[r];
      yp[(q * 4 + r) * 36 + col + 16] = acc2[r];
    }
  }
  __syncthreads();
  // epilogue: waves 0,1 each handle their tile's 16 tokens
  if (wave < 2) {
    const float* y0 = &ylds[wave * 2][0];
    const float* y1 = &ylds[wave * 2 + 1][0];
    float s[8];
    {
      const float4 a0 = *(const float4*)(y0 + col * 36 + q * 8);
      const float4 a1 = *(const float4*)(y0 + col * 36 + q * 8 + 4);
      const float4 b0 = *(const float4*)(y1 + col * 36 + q * 8);
      const float4 b1 = *(const float4*)(y1 + col * 36 + q * 8 + 4);
      s[0] = a0.x + b0.x; s[1] = a0.y + b0.y; s[2] = a0.z + b0.z; s[3] = a0.w + b0.w;
      s[4] = a1.x + b1.x; s[5] = a1.y + b1.y; s[6] = a1.z + b1.z; s[7] = a1.w + b1.w;
    }
    short8 ay;
#pragma unroll
    for (int j = 0; j < 8; ++j) ay[j] = (short)f2bf(s[j]);
    const float gm = gamma[0];
    float* pw = &ot[wave][0];
    const int tok = lane >> 2, cg2 = (lane & 3) * 4;
#pragma unroll
    for (int hh = 0; hh < 2; ++hh) {
#pragma unroll
      for (int t = 0; t < 8; ++t) {
        const short8 bw = *(const short8*)(wvlds + (hh * 8 + t) * 512 + lane * 8);
        const floatx4 d = MFMA16(ay, bw, zero, 0, 0, 0);
#pragma unroll
        for (int r = 0; r < 4; ++r) pw[(q * 4 + r) * 132 + t * 16 + col] = d[r];
      }
#pragma unroll
      for (int j = 0; j < 8; ++j) {
        const float4 v = *(const float4*)(pw + tok * 132 + cg2 + j * 16);
        const long gidx = (long)(b * NN + t0 + tok) * CC + hh * 128 + cg2 + j * 16;
        const float4 xv = *(const float4*)(x + gidx);
        float4 o;
        o.x = gm * v.x + xv.x; o.y = gm * v.y + xv.y;
        o.z = gm * v.z + xv.z; o.w = gm * v.w + xv.w;
        *(float4*)(out + gidx) = o;
      }
    }
  }
}

extern "C" void kernel_launch(void* const* d_in, const int* in_sizes, int n_in,
                              void* d_out, int out_size, void* d_ws, size_t ws_size,
                              hipStream_t stream) {
  const float* x = (const float*)d_in[0];
  const float* wf = (const float*)d_in[1];
  const float* wg = (const float*)d_in[2];
  const float* wh = (const float*)d_in[3];
  const float* wv = (const float*)d_in[4];
  const float* gamma = (const float*)d_in[5];
  float* out = (float*)d_out;

  unsigned short* f16 = (unsigned short*)d_ws;           // B*N*R (x LOG2E)
  unsigned short* g16 = f16 + (long)BB * NN * RR;        // B*N*R
  unsigned short* hT16 = g16 + (long)BB * NN * RR;       // B*R*N
  float* psum = (float*)(hT16 + (long)BB * NN * RR);     // CSEG*B*N

  k_fgh<<<BB * NN / 64, 256, 0, stream>>>(x, wf, wg, wh, f16, g16, hT16);
  k_colsum<<<CSEG * BB * 32, 256, 0, stream>>>(f16, g16, psum);
  k_pvout<<<BB * 128, 256, 0, stream>>>(f16, g16, hT16, psum, wv, x, gamma, out);
}

// Round 8
// 128.240 us; speedup vs baseline: 2.6953x; 1.1929x over previous
//
#include <hip/hip_runtime.h>

// SelfAttention2D: B=4, N=4096, C=256, R=32, fp32 in/out.
// out = gamma * ((softmax_axis1(f g^T) h) w_v) + x.
// 4 kernels: k_fgh (projections + w_v frag pack), k_colsum (softmax-axis=1
// partial denominators), k_scaleh (fold 1/colsum into h), k_pvout (PV with
// per-wave m-quarters + fused w_v projection + residual).
// All matmuls on bf16 MFMA 16x16x32. f pre-scaled by log2(e) -> raw v_exp.
// |s|*log2e < 64 << 128 so exp2 needs no max pass; exp2 values <= 2^63 are
// bf16-representable, and 1/colsum is folded into h so PV needs no scaling.
// R6 lesson: grid.sync() ~50us at 512 blocks — block-local fusion only.
// R7 lesson: PV chain (QK->exp->LDS->PV) is latency-bound; need ILP>=4/wave.

#define BB 4
#define NN 4096
#define CC 256
#define RR 32
#define CSEG 4   // n-split for colsum
#define MP 40    // P-tile row stride (ushorts)
#define LOG2E 1.44269504088896340736f

typedef short short8 __attribute__((ext_vector_type(8)));            // 8 bf16
typedef unsigned short ushort8 __attribute__((ext_vector_type(8)));
typedef float floatx4 __attribute__((ext_vector_type(4)));           // MFMA C/D

#define MFMA16 __builtin_amdgcn_mfma_f32_16x16x32_bf16

static __device__ __forceinline__ unsigned short f2bf(float f) {
  union { float f; unsigned u; } v; v.f = f;
  const unsigned r = v.u + 0x7fffu + ((v.u >> 16) & 1u);  // RNE
  return (unsigned short)(r >> 16);
}
// pack trunc-bf16(lo), trunc-bf16(hi) into one uint via v_perm_b32
static __device__ __forceinline__ unsigned bfpack(float lo, float hi) {
  return __builtin_amdgcn_perm(__float_as_uint(hi), __float_as_uint(lo), 0x07060302u);
}

// --------------- k_fgh: f,g,h = x @ {wf,wg,wh}; weights packed into LDS.
// Blocks 0..7 additionally pack w_v B-frags to global for k_pvout's epilogue.
__global__ __launch_bounds__(256) void k_fgh(
    const float* __restrict__ x, const float* __restrict__ wf,
    const float* __restrict__ wg, const float* __restrict__ wh,
    const float* __restrict__ wv,
    unsigned short* __restrict__ f16, unsigned short* __restrict__ g16,
    unsigned short* __restrict__ hT16, unsigned short* __restrict__ wvfrag) {
  __shared__ unsigned short wflds[24576];  // 48 KB: 3 mats x 16 frags x 64 lanes x 8
  const int tid = threadIdx.x, lane = tid & 63, wave = tid >> 6;
  const int col = lane & 15, q = lane >> 4;
  if (blockIdx.x < 8) {  // pack w_v B-frags: wvfrag[t*512 + lane*8 + j]
    const int base = blockIdx.x * 1024 + tid * 4;
#pragma unroll
    for (int e = 0; e < 4; ++e) {
      const int r = base + e;
      const int t = (r >> 9) & 15, l2 = (r >> 3) & 63, j = r & 7;
      wvfrag[r] = f2bf(wv[((l2 >> 4) * 8 + j) * CC + t * 16 + (l2 & 15)]);
    }
  }
  // pack w_{f,g,h}: coalesced float4 reads, scattered ds_write_b16
  for (int s4 = tid; s4 < 6144; s4 += 256) {
    const int mat = s4 >> 11;
    const int s = (s4 & 2047) << 2;          // element index within w (8192)
    const int rr = s >> 5, c = s & 31;       // w[rr][c], c % 4 == 0
    const float* w = (mat == 0) ? wf : ((mat == 1) ? wg : wh);
    const float4 v = *(const float4*)(w + s);
    const int kc = rr >> 5, q2 = (rr >> 3) & 3, j = rr & 7;
    const int base = (mat * 16 + kc * 2) * 512 + q2 * 128 + j;
    const float vv[4] = {v.x, v.y, v.z, v.w};
#pragma unroll
    for (int e = 0; e < 4; ++e) {
      const int ce = c + e;
      wflds[base + (ce >> 4) * 512 + (ce & 15) * 8] = f2bf(vv[e]);
    }
  }
  __syncthreads();
  const int t0 = blockIdx.x * 64 + wave * 16;
  short8 af[8];
  const float* xr = x + (long)(t0 + col) * CC + q * 8;
#pragma unroll
  for (int kc = 0; kc < 8; ++kc) {
    float tmp[8];
    *(float4*)(tmp) = *(const float4*)(xr + kc * 32);
    *(float4*)(tmp + 4) = *(const float4*)(xr + kc * 32 + 4);
    short8 o;
#pragma unroll
    for (int j = 0; j < 8; ++j) o[j] = (short)f2bf(tmp[j]);
    af[kc] = o;
  }
  const floatx4 zero = {0.f, 0.f, 0.f, 0.f};
  floatx4 acc[3][2];
#pragma unroll
  for (int m = 0; m < 3; ++m) { acc[m][0] = zero; acc[m][1] = zero; }
#pragma unroll
  for (int kc = 0; kc < 8; ++kc) {
#pragma unroll
    for (int mat = 0; mat < 3; ++mat) {
#pragma unroll
      for (int nt = 0; nt < 2; ++nt) {
        const short8 bf = *(const short8*)(wflds + (mat * 16 + kc * 2 + nt) * 512 + lane * 8);
        acc[mat][nt] = MFMA16(af[kc], bf, acc[mat][nt], 0, 0, 0);
      }
    }
  }
  const int b = t0 >> 12;
#pragma unroll
  for (int nt = 0; nt < 2; ++nt) {
#pragma unroll
    for (int r = 0; r < 4; ++r) {
      const int tok = t0 + q * 4 + r;
      const int n = nt * 16 + col;
      f16[(long)tok * RR + n] = f2bf(acc[0][nt][r] * LOG2E);
      g16[(long)tok * RR + n] = f2bf(acc[1][nt][r]);
      hT16[((long)b * RR + n) * NN + (tok & (NN - 1))] = f2bf(acc[2][nt][r]);
    }
  }
}

// --------------------- k_colsum: partial colsum[m] = sum_n exp2(s'[n,m])
__global__ __launch_bounds__(256) void k_colsum(
    const unsigned short* __restrict__ f16, const unsigned short* __restrict__ g16,
    float* __restrict__ psum) {
  const int tid = threadIdx.x, lane = tid & 63, wave = tid >> 6;
  const int col = lane & 15, q = lane >> 4;
  const int mblk = blockIdx.x & 31;
  const int b = (blockIdx.x >> 5) & 3;
  const int seg = blockIdx.x >> 7;
  const int m0 = mblk * 128 + wave * 32;
  const short8 bg1 = *(const short8*)(g16 + ((long)(b * NN + m0 + col)) * RR + q * 8);
  const short8 bg2 = *(const short8*)(g16 + ((long)(b * NN + m0 + 16 + col)) * RR + q * 8);
  const floatx4 zero = {0.f, 0.f, 0.f, 0.f};
  float s1 = 0.f, s2 = 0.f;
  const unsigned short* fb = f16 + ((long)b * NN + seg * (NN / CSEG)) * RR;
#pragma unroll 4
  for (int n = 0; n < NN / CSEG; n += 16) {
    const short8 af = *(const short8*)(fb + (long)(n + col) * RR + q * 8);
    const floatx4 d1 = MFMA16(af, bg1, zero, 0, 0, 0);
    const floatx4 d2 = MFMA16(af, bg2, zero, 0, 0, 0);
    s1 += __builtin_amdgcn_exp2f(d1[0]) + __builtin_amdgcn_exp2f(d1[1]) +
          __builtin_amdgcn_exp2f(d1[2]) + __builtin_amdgcn_exp2f(d1[3]);
    s2 += __builtin_amdgcn_exp2f(d2[0]) + __builtin_amdgcn_exp2f(d2[1]) +
          __builtin_amdgcn_exp2f(d2[2]) + __builtin_amdgcn_exp2f(d2[3]);
  }
  s1 += __shfl_xor(s1, 16); s1 += __shfl_xor(s1, 32);
  s2 += __shfl_xor(s2, 16); s2 += __shfl_xor(s2, 32);
  if (lane < 16) {
    psum[(long)seg * (BB * NN) + b * NN + m0 + lane] = s1;
    psum[(long)seg * (BB * NN) + b * NN + m0 + 16 + lane] = s2;
  }
}

// --------------- k_scaleh: hT'[b][r][m] = hT[b][r][m] / colsum[b][m]
__global__ __launch_bounds__(256) void k_scaleh(
    const float* __restrict__ psum, unsigned short* __restrict__ hT16) {
  const long i8 = ((long)blockIdx.x * 256 + threadIdx.x) * 8;
  const int b = (int)(i8 >> 17);       // / (RR*NN)
  const int m = (int)(i8 & (NN - 1));
  float cs[8] = {0.f, 0.f, 0.f, 0.f, 0.f, 0.f, 0.f, 0.f};
#pragma unroll
  for (int sg = 0; sg < CSEG; ++sg) {
    const float* p = psum + (long)sg * (BB * NN) + b * NN + m;
    const float4 a = *(const float4*)p;
    const float4 c = *(const float4*)(p + 4);
    cs[0] += a.x; cs[1] += a.y; cs[2] += a.z; cs[3] += a.w;
    cs[4] += c.x; cs[5] += c.y; cs[6] += c.z; cs[7] += c.w;
  }
  const ushort8 hv = *(const ushort8*)(hT16 + i8);
  ushort8 o;
#pragma unroll
  for (int j = 0; j < 8; ++j) {
    const float h = __uint_as_float(((unsigned)hv[j]) << 16);
    o[j] = f2bf(h * __builtin_amdgcn_rcpf(cs[j]));
  }
  *(ushort8*)(hT16 + i8) = o;
}

// --------- k_pvout: block = 32 tokens; wave w = m-quarter w (ILP-4 PV) +
// LDS partial-y merge + fused y@w_v + gamma*() + x residual.
struct PvU {  // phase-exclusive LDS (syncthreads-separated)
  union {
    unsigned short pt[4][32 * MP];  // 10 KB: P^T tiles (PV phase)
    float ot[4][16 * 132];          // 33 KB: out transpose (epilogue)
  };
};
#define C_ADDR(TN, TM) (((TN) + col) * MP + (TM) + q * 4)
__global__ __launch_bounds__(256, 2) void k_pvout(
    const unsigned short* __restrict__ f16, const unsigned short* __restrict__ g16,
    const unsigned short* __restrict__ hT16, const unsigned short* __restrict__ wvfrag,
    const float* __restrict__ x, const float* __restrict__ gamma,
    float* __restrict__ out) {
  __shared__ float ylds[4][32 * 36];  // 18 KB: per-wave y partials
  __shared__ PvU u;
  const int tid = threadIdx.x, lane = tid & 63, wave = tid >> 6;
  const int col = lane & 15, q = lane >> 4;
  const int b = blockIdx.x >> 7;
  const int t0 = (blockIdx.x & 127) * 32;  // token base (in-batch), 32 tokens
  const floatx4 zero = {0.f, 0.f, 0.f, 0.f};
  // B-frags of S^T: f rows for the block's 32 tokens (loop-invariant)
  const short8 af1 = *(const short8*)(f16 + ((long)(b * NN + t0 + col)) * RR + q * 8);
  const short8 af2 = *(const short8*)(f16 + ((long)(b * NN + t0 + 16 + col)) * RR + q * 8);
  floatx4 a11 = zero, a12 = zero, a21 = zero, a22 = zero;
  unsigned short* pt = &u.pt[wave][0];
  const unsigned short* gb = g16 + (long)b * NN * RR;
  const unsigned short* hb = hT16 + (long)b * RR * NN;
  const int mq = wave * 1024;  // this wave's m-quarter
#pragma unroll 2
  for (int mi = 0; mi < 1024; mi += 32) {
    const int m0 = mq + mi;
    const short8 bg1 = *(const short8*)(gb + (long)(m0 + col) * RR + q * 8);
    const short8 bg2 = *(const short8*)(gb + (long)(m0 + 16 + col) * RR + q * 8);
    // S^T: A=g(m rows), B=f(n cols) -> lane(q,col): s'[n][m = m0 + q*4+r]
    const floatx4 d00 = MFMA16(bg1, af1, zero, 0, 0, 0);  // n-blk 0, m-blk 0
    const floatx4 d01 = MFMA16(bg2, af1, zero, 0, 0, 0);  // n-blk 0, m-blk 16
    const floatx4 d10 = MFMA16(bg1, af2, zero, 0, 0, 0);  // n-blk 16, m-blk 0
    const floatx4 d11 = MFMA16(bg2, af2, zero, 0, 0, 0);  // n-blk 16, m-blk 16
    // P' = exp2(s') (1/colsum already folded into h')
    float w0, w1, w2, w3;
    w0 = __builtin_amdgcn_exp2f(d00[0]); w1 = __builtin_amdgcn_exp2f(d00[1]);
    w2 = __builtin_amdgcn_exp2f(d00[2]); w3 = __builtin_amdgcn_exp2f(d00[3]);
    *(uint2*)(pt + C_ADDR(0, 0)) = make_uint2(bfpack(w0, w1), bfpack(w2, w3));
    w0 = __builtin_amdgcn_exp2f(d01[0]); w1 = __builtin_amdgcn_exp2f(d01[1]);
    w2 = __builtin_amdgcn_exp2f(d01[2]); w3 = __builtin_amdgcn_exp2f(d01[3]);
    *(uint2*)(pt + C_ADDR(0, 16)) = make_uint2(bfpack(w0, w1), bfpack(w2, w3));
    w0 = __builtin_amdgcn_exp2f(d10[0]); w1 = __builtin_amdgcn_exp2f(d10[1]);
    w2 = __builtin_amdgcn_exp2f(d10[2]); w3 = __builtin_amdgcn_exp2f(d10[3]);
    *(uint2*)(pt + C_ADDR(16, 0)) = make_uint2(bfpack(w0, w1), bfpack(w2, w3));
    w0 = __builtin_amdgcn_exp2f(d11[0]); w1 = __builtin_amdgcn_exp2f(d11[1]);
    w2 = __builtin_amdgcn_exp2f(d11[2]); w3 = __builtin_amdgcn_exp2f(d11[3]);
    *(uint2*)(pt + C_ADDR(16, 16)) = make_uint2(bfpack(w0, w1), bfpack(w2, w3));
    // read back as PV A-frags (same wave, lgkmcnt-ordered)
    const short8 ap1 = *(const short8*)(pt + col * MP + q * 8);
    const short8 ap2 = *(const short8*)(pt + (col + 16) * MP + q * 8);
    const short8 bh1 = *(const short8*)(hb + (long)col * NN + m0 + q * 8);
    const short8 bh2 = *(const short8*)(hb + (long)(col + 16) * NN + m0 + q * 8);
    a11 = MFMA16(ap1, bh1, a11, 0, 0, 0);
    a12 = MFMA16(ap1, bh2, a12, 0, 0, 0);
    a21 = MFMA16(ap2, bh1, a21, 0, 0, 0);
    a22 = MFMA16(ap2, bh2, a22, 0, 0, 0);
  }
  // stash y partial for this m-quarter: [wave][token 0..31][r 0..31]
  {
    float* yp = &ylds[wave][0];
#pragma unroll
    for (int r = 0; r < 4; ++r) {
      yp[(q * 4 + r) * 36 + col] = a11[r];
      yp[(q * 4 + r) * 36 + col + 16] = a12[r];
      yp[(16 + q * 4 + r) * 36 + col] = a21[r];
      yp[(16 + q * 4 + r) * 36 + col + 16] = a22[r];
    }
  }
  __syncthreads();
  // epilogue: wave -> (tile = w&1: 16 tokens, hh = w>>1: 128-channel half)
  {
    const int tile = wave & 1, hh = wave >> 1;
    float s[8] = {0.f, 0.f, 0.f, 0.f, 0.f, 0.f, 0.f, 0.f};
#pragma unroll
    for (int w2 = 0; w2 < 4; ++w2) {
      const float* yp = &ylds[w2][(tile * 16 + col) * 36 + q * 8];
      const float4 u0 = *(const float4*)yp;
      const float4 u1 = *(const float4*)(yp + 4);
      s[0] += u0.x; s[1] += u0.y; s[2] += u0.z; s[3] += u0.w;
      s[4] += u1.x; s[5] += u1.y; s[6] += u1.z; s[7] += u1.w;
    }
    short8 ay;
#pragma unroll
    for (int j = 0; j < 8; ++j) ay[j] = (short)f2bf(s[j]);
    const float gm = gamma[0];
    float* pw = &u.ot[wave][0];
#pragma unroll
    for (int t = 0; t < 8; ++t) {
      const short8 bw = *(const short8*)(wvfrag + (hh * 8 + t) * 512 + lane * 8);
      const floatx4 d = MFMA16(ay, bw, zero, 0, 0, 0);
#pragma unroll
      for (int r = 0; r < 4; ++r) pw[(q * 4 + r) * 132 + t * 16 + col] = d[r];
    }
    const int tok = lane >> 2, cg2 = (lane & 3) * 4;
#pragma unroll
    for (int j = 0; j < 8; ++j) {
      const float4 v = *(const float4*)(pw + tok * 132 + cg2 + j * 16);
      const long gidx = (long)(b * NN + t0 + tile * 16 + tok) * CC + hh * 128 + cg2 + j * 16;
      const float4 xv = *(const float4*)(x + gidx);
      float4 o;
      o.x = gm * v.x + xv.x; o.y = gm * v.y + xv.y;
      o.z = gm * v.z + xv.z; o.w = gm * v.w + xv.w;
      *(float4*)(out + gidx) = o;
    }
  }
}

extern "C" void kernel_launch(void* const* d_in, const int* in_sizes, int n_in,
                              void* d_out, int out_size, void* d_ws, size_t ws_size,
                              hipStream_t stream) {
  const float* x = (const float*)d_in[0];
  const float* wf = (const float*)d_in[1];
  const float* wg = (const float*)d_in[2];
  const float* wh = (const float*)d_in[3];
  const float* wv = (const float*)d_in[4];
  const float* gamma = (const float*)d_in[5];
  float* out = (float*)d_out;

  unsigned short* f16 = (unsigned short*)d_ws;           // B*N*R (x LOG2E)
  unsigned short* g16 = f16 + (long)BB * NN * RR;        // B*N*R
  unsigned short* hT16 = g16 + (long)BB * NN * RR;       // B*R*N (scaled in-place)
  unsigned short* wvfrag = hT16 + (long)BB * NN * RR;    // 8192
  float* psum = (float*)(wvfrag + 8192);                 // CSEG*B*N

  k_fgh<<<BB * NN / 64, 256, 0, stream>>>(x, wf, wg, wh, wv, f16, g16, hT16, wvfrag);
  k_colsum<<<CSEG * BB * 32, 256, 0, stream>>>(f16, g16, psum);
  k_scaleh<<<BB * RR * NN / 2048, 256, 0, stream>>>(psum, hT16);
  k_pvout<<<BB * 128, 256, 0, stream>>>(f16, g16, hT16, wvfrag, x, gamma, out);
}

// Round 9
// 124.254 us; speedup vs baseline: 2.7817x; 1.0321x over previous
//
#include <hip/hip_runtime.h>

// SelfAttention2D: B=4, N=4096, C=256, R=32, fp32 in/out.
// out = gamma * ((softmax_axis1(f g^T) h) w_v) + x.
// 5 kernels: k_prep (weight B-frag pack), k_fgh (projections), k_colsum
// (softmax-axis=1 partial denominators), k_scaleh (fold 1/colsum into h),
// k_pvout (PV with per-wave m-quarters + fused w_v projection + residual).
// All matmuls on bf16 MFMA 16x16x32. f pre-scaled by log2(e) -> raw v_exp.
// |s|*log2e < 64 << 128 so exp2 needs no max pass; exp2 <= 2^63 fits bf16;
// 1/colsum folded into h so PV needs no per-element scaling.
// R6 lesson: grid.sync() ~50us at 512 blocks — block-local fusion only.
// R7 lesson: PV chain (QK->exp->LDS->PV) is latency-bound; need ILP>=4/wave.
// R8 lesson: in-block scattered b16 weight packs are LDS-port-expensive;
// pack once in k_prep, stage with contiguous copies. Keep LDS small for
// occupancy (epilogue transposes 2 D-tiles at a time through P-tile scratch).

#define BB 4
#define NN 4096
#define CC 256
#define RR 32
#define CSEG 4   // n-split for colsum
#define MP 40    // P-tile row stride (ushorts)
#define LOG2E 1.44269504088896340736f

typedef short short8 __attribute__((ext_vector_type(8)));            // 8 bf16
typedef unsigned short ushort8 __attribute__((ext_vector_type(8)));
typedef float floatx4 __attribute__((ext_vector_type(4)));           // MFMA C/D

#define MFMA16 __builtin_amdgcn_mfma_f32_16x16x32_bf16

static __device__ __forceinline__ unsigned short f2bf(float f) {
  union { float f; unsigned u; } v; v.f = f;
  const unsigned r = v.u + 0x7fffu + ((v.u >> 16) & 1u);  // RNE
  return (unsigned short)(r >> 16);
}
// pack trunc-bf16(lo), trunc-bf16(hi) into one uint via v_perm_b32
static __device__ __forceinline__ unsigned bfpack(float lo, float hi) {
  return __builtin_amdgcn_perm(__float_as_uint(hi), __float_as_uint(lo), 0x07060302u);
}

// ------------------------------ k_prep: pack weights into B-frag bf16 layout
// wfrag[mat][kc*2+nt][lane][j] = w_mat[kc*32 + (lane>>4)*8 + j][nt*16 + (lane&15)]
// wvfrag[t][lane][j]           = w_v[(lane>>4)*8 + j][t*16 + (lane&15)]
__global__ __launch_bounds__(256) void k_prep(
    const float* __restrict__ wf, const float* __restrict__ wg,
    const float* __restrict__ wh, const float* __restrict__ wv,
    unsigned short* __restrict__ wfrag, unsigned short* __restrict__ wvfrag) {
  const int idx = blockIdx.x * 256 + threadIdx.x;  // 0..32767
  const int lane = (idx >> 3) & 63;
  const int j = idx & 7;
  const int col = lane & 15, q = lane >> 4;
  if (idx < 24576) {
    const int mat = idx >> 13;
    const int fid = (idx >> 9) & 15;
    const int kc = fid >> 1, nt = fid & 1;
    const float* w = (mat == 0) ? wf : ((mat == 1) ? wg : wh);
    wfrag[idx] = f2bf(w[(kc * 32 + q * 8 + j) * RR + nt * 16 + col]);
  } else {
    const int r = idx - 24576;
    const int t = (r >> 9) & 15;
    wvfrag[r] = f2bf(wv[(q * 8 + j) * CC + t * 16 + col]);
  }
}

// --------------- k_fgh: f,g,h = x @ {wf,wg,wh}; packed frags staged to LDS
__global__ __launch_bounds__(256) void k_fgh(
    const float* __restrict__ x, const unsigned short* __restrict__ wfrag,
    unsigned short* __restrict__ f16, unsigned short* __restrict__ g16,
    unsigned short* __restrict__ hT16) {
  __shared__ unsigned short wflds[24576];  // 48 KB packed frags
  const int tid = threadIdx.x, lane = tid & 63, wave = tid >> 6;
  const int col = lane & 15, q = lane >> 4;
  {  // conflict-free contiguous stage: 3072 uint4
    const uint4* src = (const uint4*)wfrag;
    uint4* dst = (uint4*)wflds;
#pragma unroll
    for (int i = 0; i < 12; ++i) dst[tid + i * 256] = src[tid + i * 256];
  }
  __syncthreads();
  const int t0 = blockIdx.x * 64 + wave * 16;
  short8 af[8];
  const float* xr = x + (long)(t0 + col) * CC + q * 8;
#pragma unroll
  for (int kc = 0; kc < 8; ++kc) {
    float tmp[8];
    *(float4*)(tmp) = *(const float4*)(xr + kc * 32);
    *(float4*)(tmp + 4) = *(const float4*)(xr + kc * 32 + 4);
    short8 o;
#pragma unroll
    for (int j = 0; j < 8; ++j) o[j] = (short)f2bf(tmp[j]);
    af[kc] = o;
  }
  const floatx4 zero = {0.f, 0.f, 0.f, 0.f};
  floatx4 acc[3][2];
#pragma unroll
  for (int m = 0; m < 3; ++m) { acc[m][0] = zero; acc[m][1] = zero; }
#pragma unroll
  for (int kc = 0; kc < 8; ++kc) {
#pragma unroll
    for (int mat = 0; mat < 3; ++mat) {
#pragma unroll
      for (int nt = 0; nt < 2; ++nt) {
        const short8 bf = *(const short8*)(wflds + (mat * 16 + kc * 2 + nt) * 512 + lane * 8);
        acc[mat][nt] = MFMA16(af[kc], bf, acc[mat][nt], 0, 0, 0);
      }
    }
  }
  const int b = t0 >> 12;
#pragma unroll
  for (int nt = 0; nt < 2; ++nt) {
#pragma unroll
    for (int r = 0; r < 4; ++r) {
      const int tok = t0 + q * 4 + r;
      const int n = nt * 16 + col;
      f16[(long)tok * RR + n] = f2bf(acc[0][nt][r] * LOG2E);
      g16[(long)tok * RR + n] = f2bf(acc[1][nt][r]);
      hT16[((long)b * RR + n) * NN + (tok & (NN - 1))] = f2bf(acc[2][nt][r]);
    }
  }
}

// --------------------- k_colsum: partial colsum[m] = sum_n exp2(s'[n,m])
__global__ __launch_bounds__(256) void k_colsum(
    const unsigned short* __restrict__ f16, const unsigned short* __restrict__ g16,
    float* __restrict__ psum) {
  const int tid = threadIdx.x, lane = tid & 63, wave = tid >> 6;
  const int col = lane & 15, q = lane >> 4;
  const int mblk = blockIdx.x & 31;
  const int b = (blockIdx.x >> 5) & 3;
  const int seg = blockIdx.x >> 7;
  const int m0 = mblk * 128 + wave * 32;
  const short8 bg1 = *(const short8*)(g16 + ((long)(b * NN + m0 + col)) * RR + q * 8);
  const short8 bg2 = *(const short8*)(g16 + ((long)(b * NN + m0 + 16 + col)) * RR + q * 8);
  const floatx4 zero = {0.f, 0.f, 0.f, 0.f};
  float s1 = 0.f, s2 = 0.f;
  const unsigned short* fb = f16 + ((long)b * NN + seg * (NN / CSEG)) * RR;
#pragma unroll 4
  for (int n = 0; n < NN / CSEG; n += 16) {
    const short8 af = *(const short8*)(fb + (long)(n + col) * RR + q * 8);
    const floatx4 d1 = MFMA16(af, bg1, zero, 0, 0, 0);
    const floatx4 d2 = MFMA16(af, bg2, zero, 0, 0, 0);
    s1 += __builtin_amdgcn_exp2f(d1[0]) + __builtin_amdgcn_exp2f(d1[1]) +
          __builtin_amdgcn_exp2f(d1[2]) + __builtin_amdgcn_exp2f(d1[3]);
    s2 += __builtin_amdgcn_exp2f(d2[0]) + __builtin_amdgcn_exp2f(d2[1]) +
          __builtin_amdgcn_exp2f(d2[2]) + __builtin_amdgcn_exp2f(d2[3]);
  }
  s1 += __shfl_xor(s1, 16); s1 += __shfl_xor(s1, 32);
  s2 += __shfl_xor(s2, 16); s2 += __shfl_xor(s2, 32);
  if (lane < 16) {
    psum[(long)seg * (BB * NN) + b * NN + m0 + lane] = s1;
    psum[(long)seg * (BB * NN) + b * NN + m0 + 16 + lane] = s2;
  }
}

// --------------- k_scaleh: hT'[b][r][m] = hT[b][r][m] / colsum[b][m]
__global__ __launch_bounds__(256) void k_scaleh(
    const float* __restrict__ psum, unsigned short* __restrict__ hT16) {
  const long i8 = ((long)blockIdx.x * 256 + threadIdx.x) * 8;
  const int b = (int)(i8 >> 17);       // / (RR*NN)
  const int m = (int)(i8 & (NN - 1));
  float cs[8] = {0.f, 0.f, 0.f, 0.f, 0.f, 0.f, 0.f, 0.f};
#pragma unroll
  for (int sg = 0; sg < CSEG; ++sg) {
    const float* p = psum + (long)sg * (BB * NN) + b * NN + m;
    const float4 a = *(const float4*)p;
    const float4 c = *(const float4*)(p + 4);
    cs[0] += a.x; cs[1] += a.y; cs[2] += a.z; cs[3] += a.w;
    cs[4] += c.x; cs[5] += c.y; cs[6] += c.z; cs[7] += c.w;
  }
  const ushort8 hv = *(const ushort8*)(hT16 + i8);
  ushort8 o;
#pragma unroll
  for (int j = 0; j < 8; ++j) {
    const float h = __uint_as_float(((unsigned)hv[j]) << 16);
    o[j] = f2bf(h * __builtin_amdgcn_rcpf(cs[j]));
  }
  *(ushort8*)(hT16 + i8) = o;
}

// --------- k_pvout: block = 32 tokens; wave w = m-quarter w (ILP-4 PV) +
// LDS partial-y merge + fused y@w_v + gamma*() + x residual.
// LDS 28 KB -> 4-5 blocks/CU; epilogue reuses P-tile scratch 2 D-tiles/chunk.
#define C_ADDR(TN, TM) (((TN) + col) * MP + (TM) + q * 4)
__global__ __launch_bounds__(256, 4) void k_pvout(
    const unsigned short* __restrict__ f16, const unsigned short* __restrict__ g16,
    const unsigned short* __restrict__ hT16, const unsigned short* __restrict__ wvfrag,
    const float* __restrict__ x, const float* __restrict__ gamma,
    float* __restrict__ out) {
  __shared__ float ylds[4][32 * 36];              // 18 KB: per-wave y partials
  __shared__ unsigned short pt_all[4][32 * MP];   // 10 KB: P^T / epilogue scratch
  const int tid = threadIdx.x, lane = tid & 63, wave = tid >> 6;
  const int col = lane & 15, q = lane >> 4;
  const int b = blockIdx.x >> 7;
  const int t0 = (blockIdx.x & 127) * 32;  // token base (in-batch), 32 tokens
  const floatx4 zero = {0.f, 0.f, 0.f, 0.f};
  // B-frags of S^T: f rows for the block's 32 tokens (loop-invariant)
  const short8 af1 = *(const short8*)(f16 + ((long)(b * NN + t0 + col)) * RR + q * 8);
  const short8 af2 = *(const short8*)(f16 + ((long)(b * NN + t0 + 16 + col)) * RR + q * 8);
  floatx4 a11 = zero, a12 = zero, a21 = zero, a22 = zero;
  unsigned short* pt = &pt_all[wave][0];
  const unsigned short* gb = g16 + (long)b * NN * RR;
  const unsigned short* hb = hT16 + (long)b * RR * NN;
  const int mq = wave * 1024;  // this wave's m-quarter
#pragma unroll 2
  for (int mi = 0; mi < 1024; mi += 32) {
    const int m0 = mq + mi;
    const short8 bg1 = *(const short8*)(gb + (long)(m0 + col) * RR + q * 8);
    const short8 bg2 = *(const short8*)(gb + (long)(m0 + 16 + col) * RR + q * 8);
    // S^T: A=g(m rows), B=f(n cols) -> lane(q,col): s'[n][m = m0 + q*4+r]
    const floatx4 d00 = MFMA16(bg1, af1, zero, 0, 0, 0);  // n-blk 0, m-blk 0
    const floatx4 d01 = MFMA16(bg2, af1, zero, 0, 0, 0);  // n-blk 0, m-blk 16
    const floatx4 d10 = MFMA16(bg1, af2, zero, 0, 0, 0);  // n-blk 16, m-blk 0
    const floatx4 d11 = MFMA16(bg2, af2, zero, 0, 0, 0);  // n-blk 16, m-blk 16
    // P' = exp2(s') (1/colsum already folded into h')
    float w0, w1, w2, w3;
    w0 = __builtin_amdgcn_exp2f(d00[0]); w1 = __builtin_amdgcn_exp2f(d00[1]);
    w2 = __builtin_amdgcn_exp2f(d00[2]); w3 = __builtin_amdgcn_exp2f(d00[3]);
    *(uint2*)(pt + C_ADDR(0, 0)) = make_uint2(bfpack(w0, w1), bfpack(w2, w3));
    w0 = __builtin_amdgcn_exp2f(d01[0]); w1 = __builtin_amdgcn_exp2f(d01[1]);
    w2 = __builtin_amdgcn_exp2f(d01[2]); w3 = __builtin_amdgcn_exp2f(d01[3]);
    *(uint2*)(pt + C_ADDR(0, 16)) = make_uint2(bfpack(w0, w1), bfpack(w2, w3));
    w0 = __builtin_amdgcn_exp2f(d10[0]); w1 = __builtin_amdgcn_exp2f(d10[1]);
    w2 = __builtin_amdgcn_exp2f(d10[2]); w3 = __builtin_amdgcn_exp2f(d10[3]);
    *(uint2*)(pt + C_ADDR(16, 0)) = make_uint2(bfpack(w0, w1), bfpack(w2, w3));
    w0 = __builtin_amdgcn_exp2f(d11[0]); w1 = __builtin_amdgcn_exp2f(d11[1]);
    w2 = __builtin_amdgcn_exp2f(d11[2]); w3 = __builtin_amdgcn_exp2f(d11[3]);
    *(uint2*)(pt + C_ADDR(16, 16)) = make_uint2(bfpack(w0, w1), bfpack(w2, w3));
    // read back as PV A-frags (same wave, lgkmcnt-ordered)
    const short8 ap1 = *(const short8*)(pt + col * MP + q * 8);
    const short8 ap2 = *(const short8*)(pt + (col + 16) * MP + q * 8);
    const short8 bh1 = *(const short8*)(hb + (long)col * NN + m0 + q * 8);
    const short8 bh2 = *(const short8*)(hb + (long)(col + 16) * NN + m0 + q * 8);
    a11 = MFMA16(ap1, bh1, a11, 0, 0, 0);
    a12 = MFMA16(ap1, bh2, a12, 0, 0, 0);
    a21 = MFMA16(ap2, bh1, a21, 0, 0, 0);
    a22 = MFMA16(ap2, bh2, a22, 0, 0, 0);
  }
  // stash y partial for this m-quarter: [wave][token 0..31][r 0..31]
  {
    float* yp = &ylds[wave][0];
#pragma unroll
    for (int r = 0; r < 4; ++r) {
      yp[(q * 4 + r) * 36 + col] = a11[r];
      yp[(q * 4 + r) * 36 + col + 16] = a12[r];
      yp[(16 + q * 4 + r) * 36 + col] = a21[r];
      yp[(16 + q * 4 + r) * 36 + col + 16] = a22[r];
    }
  }
  __syncthreads();
  // epilogue: wave -> (tile = w&1: 16 tokens, hh = w>>1: 128-channel half);
  // 2 D-tiles per chunk through pt scratch (2304 B <= 2560 B)
  {
    const int tile = wave & 1, hh = wave >> 1;
    float s[8] = {0.f, 0.f, 0.f, 0.f, 0.f, 0.f, 0.f, 0.f};
#pragma unroll
    for (int w2 = 0; w2 < 4; ++w2) {
      const float* yp = &ylds[w2][(tile * 16 + col) * 36 + q * 8];
      const float4 u0 = *(const float4*)yp;
      const float4 u1 = *(const float4*)(yp + 4);
      s[0] += u0.x; s[1] += u0.y; s[2] += u0.z; s[3] += u0.w;
      s[4] += u1.x; s[5] += u1.y; s[6] += u1.z; s[7] += u1.w;
    }
    short8 ay;
#pragma unroll
    for (int j = 0; j < 8; ++j) ay[j] = (short)f2bf(s[j]);
    const float gm = gamma[0];
    float* sc = (float*)pt;  // per-wave scratch, 16 x 36 floats
    const int row = lane >> 2, c4 = (lane & 3) * 4;
#pragma unroll
    for (int tp = 0; tp < 8; tp += 2) {
      const short8 bw0 = *(const short8*)(wvfrag + (hh * 8 + tp) * 512 + lane * 8);
      const short8 bw1 = *(const short8*)(wvfrag + (hh * 8 + tp + 1) * 512 + lane * 8);
      const floatx4 d0 = MFMA16(ay, bw0, zero, 0, 0, 0);
      const floatx4 d1 = MFMA16(ay, bw1, zero, 0, 0, 0);
#pragma unroll
      for (int r = 0; r < 4; ++r) {
        sc[(q * 4 + r) * 36 + col] = d0[r];
        sc[(q * 4 + r) * 36 + col + 16] = d1[r];
      }
      // same-wave readback, row-major -> coalesced float4 global I/O
#pragma unroll
      for (int j = 0; j < 2; ++j) {
        const float4 v = *(const float4*)(sc + row * 36 + c4 + j * 16);
        const long gidx = (long)(b * NN + t0 + tile * 16 + row) * CC +
                          hh * 128 + tp * 16 + j * 16 + c4;
        const float4 xv = *(const float4*)(x + gidx);
        float4 o;
        o.x = gm * v.x + xv.x; o.y = gm * v.y + xv.y;
        o.z = gm * v.z + xv.z; o.w = gm * v.w + xv.w;
        *(float4*)(out + gidx) = o;
      }
    }
  }
}

extern "C" void kernel_launch(void* const* d_in, const int* in_sizes, int n_in,
                              void* d_out, int out_size, void* d_ws, size_t ws_size,
                              hipStream_t stream) {
  const float* x = (const float*)d_in[0];
  const float* wf = (const float*)d_in[1];
  const float* wg = (const float*)d_in[2];
  const float* wh = (const float*)d_in[3];
  const float* wv = (const float*)d_in[4];
  const float* gamma = (const float*)d_in[5];
  float* out = (float*)d_out;

  unsigned short* f16 = (unsigned short*)d_ws;           // B*N*R (x LOG2E)
  unsigned short* g16 = f16 + (long)BB * NN * RR;        // B*N*R
  unsigned short* hT16 = g16 + (long)BB * NN * RR;       // B*R*N (scaled in-place)
  unsigned short* wfrag = hT16 + (long)BB * NN * RR;     // 24576
  unsigned short* wvfrag = wfrag + 24576;                // 8192
  float* psum = (float*)(wvfrag + 8192);                 // CSEG*B*N

  k_prep<<<128, 256, 0, stream>>>(wf, wg, wh, wv, wfrag, wvfrag);
  k_fgh<<<BB * NN / 64, 256, 0, stream>>>(x, wfrag, f16, g16, hT16);
  k_colsum<<<CSEG * BB * 32, 256, 0, stream>>>(f16, g16, psum);
  k_scaleh<<<BB * RR * NN / 2048, 256, 0, stream>>>(psum, hT16);
  k_pvout<<<BB * 128, 256, 0, stream>>>(f16, g16, hT16, wvfrag, x, gamma, out);
}